// Round 1
// baseline (165.186 us; speedup 1.0000x reference)
//
#include <hip/hip_runtime.h>

// out[i] = gen_map[x_gen[i]] + c * x_max_clock_speed[i] + d * x_max_tdp[i]
// N = 8388608 (2^23), NUM_GENS = 1024. Memory-bound elementwise:
// 16 B/elem mandatory traffic -> ~134 MB -> ~21 us at 6.3 TB/s.

#define NUM_GENS 1024

__global__ __launch_bounds__(256)
void Model_64364379898151_kernel(const int* __restrict__ x_gen,
                                 const float* __restrict__ x_clock,
                                 const float* __restrict__ x_tdp,
                                 const float* __restrict__ gen_map,
                                 const float* __restrict__ c_ptr,
                                 const float* __restrict__ d_ptr,
                                 float* __restrict__ out,
                                 int n_vec)  // number of vec4 groups
{
    // Stage the 4 KB gather table into LDS (random gather across 32 banks;
    // ~2 lanes/bank aliasing is free on gfx950).
    __shared__ float s_map[NUM_GENS];
    for (int i = threadIdx.x; i < NUM_GENS; i += 256)
        s_map[i] = gen_map[i];
    __syncthreads();

    const float c = c_ptr[0];
    const float d = d_ptr[0];

    int vid = blockIdx.x * 256 + threadIdx.x;
    if (vid >= n_vec) return;  // exact grid in practice (2^23 / 4 / 256 = 8192)

    const int4   g  = ((const int4*)  x_gen  )[vid];
    const float4 cs = ((const float4*)x_clock)[vid];
    const float4 td = ((const float4*)x_tdp  )[vid];

    float4 o;
    o.x = s_map[g.x] + c * cs.x + d * td.x;
    o.y = s_map[g.y] + c * cs.y + d * td.y;
    o.z = s_map[g.z] + c * cs.z + d * td.z;
    o.w = s_map[g.w] + c * cs.w + d * td.w;

    ((float4*)out)[vid] = o;
}

extern "C" void kernel_launch(void* const* d_in, const int* in_sizes, int n_in,
                              void* d_out, int out_size, void* d_ws, size_t ws_size,
                              hipStream_t stream) {
    // setup_inputs() order:
    // 0: x_gen (int32, N)         1: x_ix (int32, N) -- unused
    // 2: x_max_clock_speed (f32)  3: x_max_tdp (f32)
    // 4: gen_map (f32, 1024)
    // 5: b (f32 scalar, unused)   6: c (f32 scalar)   7: d (f32 scalar)
    const int*   x_gen   = (const int*)  d_in[0];
    const float* x_clock = (const float*)d_in[2];
    const float* x_tdp   = (const float*)d_in[3];
    const float* gen_map = (const float*)d_in[4];
    const float* c_ptr   = (const float*)d_in[6];
    const float* d_ptr   = (const float*)d_in[7];
    float* out = (float*)d_out;

    const int n = in_sizes[0];          // 8388608
    const int n_vec = n / 4;            // divisible: 2^23 / 4 = 2^21
    const int block = 256;
    const int grid = (n_vec + block - 1) / block;   // 8192

    Model_64364379898151_kernel<<<grid, block, 0, stream>>>(
        x_gen, x_clock, x_tdp, gen_map, c_ptr, d_ptr, out, n_vec);
}